// Round 4
// baseline (769.896 us; speedup 1.0000x reference)
//
#include <hip/hip_runtime.h>
#include <hip/hip_bf16.h>
#include <cstdint>

// Problem constants (B=4, S=2048, H=2048, I=1024, E=8, K=2)
#define T_TOKENS 8192
#define H_DIM 2048
#define I_DIM 1024
#define N_EXPERTS 8
#define PAIRS (T_TOKENS * 2)
#define TOT_TILES 144            // sum_b ceil(n_b/128) <= 16384/128 + 16
#define TOT_ROWS (TOT_TILES * 128)

using f32x4 = __attribute__((ext_vector_type(4))) float;
using bfv   = __attribute__((ext_vector_type(8))) short;   // MFMA a/b frag (8 bf16)
using u16x8 = __attribute__((ext_vector_type(8))) unsigned short;
using u32x4 = __attribute__((ext_vector_type(4))) unsigned int;

typedef __attribute__((address_space(3))) unsigned int lds_u32;
typedef __attribute__((address_space(1))) unsigned int glb_u32;

__device__ __forceinline__ void gll16(const void* g, void* l) {
  __builtin_amdgcn_global_load_lds((const glb_u32*)g, (lds_u32*)l, 16, 0, 0);
}
#define SB0() __builtin_amdgcn_sched_barrier(0)
#define BAR() __builtin_amdgcn_s_barrier()

__device__ inline unsigned short f2bf(float f) {
  unsigned int u = __float_as_uint(f);
  u += 0x7FFFu + ((u >> 16) & 1u);          // RTN-even
  return (unsigned short)(u >> 16);
}
__device__ __forceinline__ unsigned int pkbf(float lo, float hi) {
  unsigned int r;
  asm("v_cvt_pk_bf16_f32 %0, %1, %2" : "=v"(r) : "v"(lo), "v"(hi));
  return r;
}

// ---------------- fp32 -> bf16 bulk convert ----------------
__global__ __launch_bounds__(256) void moe_convert_kernel(
    const float* __restrict__ src, unsigned short* __restrict__ dst, int n8) {
  int i = blockIdx.x * 256 + threadIdx.x;
  if (i >= n8) return;
  size_t o = (size_t)i * 8;
  f32x4 a = *reinterpret_cast<const f32x4*>(src + o);
  f32x4 b = *reinterpret_cast<const f32x4*>(src + o + 4);
  u16x8 r = {f2bf(a[0]), f2bf(a[1]), f2bf(a[2]), f2bf(a[3]),
             f2bf(b[0]), f2bf(b[1]), f2bf(b[2]), f2bf(b[3])};
  *reinterpret_cast<u16x8*>(dst + o) = r;
}

// ---------------- Router: RMSNorm folded into logits, softmax, top-2 (fp32) ----------------
__global__ __launch_bounds__(256) void moe_router_kernel(
    const float* __restrict__ X, const float* __restrict__ norm_w,
    const float* __restrict__ rw, float* __restrict__ probs,
    float* __restrict__ topw, int* __restrict__ topi,
    unsigned int* __restrict__ counts) {
  int t = blockIdx.x;
  int tid = threadIdx.x;
  const float* x = X + (size_t)t * H_DIM;
  int base = tid * 8;
  f32x4 v0 = *reinterpret_cast<const f32x4*>(x + base);
  f32x4 v1 = *reinterpret_cast<const f32x4*>(x + base + 4);
  f32x4 nw0 = *reinterpret_cast<const f32x4*>(norm_w + base);
  f32x4 nw1 = *reinterpret_cast<const f32x4*>(norm_w + base + 4);
  float vals[9];
  vals[0] = v0[0]*v0[0] + v0[1]*v0[1] + v0[2]*v0[2] + v0[3]*v0[3]
          + v1[0]*v1[0] + v1[1]*v1[1] + v1[2]*v1[2] + v1[3]*v1[3];
  f32x4 a0 = v0 * nw0, a1 = v1 * nw1;
#pragma unroll
  for (int e = 0; e < 8; ++e) {
    const float* r = rw + e * H_DIM + base;
    f32x4 r0 = *reinterpret_cast<const f32x4*>(r);
    f32x4 r1 = *reinterpret_cast<const f32x4*>(r + 4);
    f32x4 d = a0 * r0 + a1 * r1;
    vals[e + 1] = d[0] + d[1] + d[2] + d[3];
  }
#pragma unroll
  for (int v = 0; v < 9; ++v) {
    float s = vals[v];
#pragma unroll
    for (int off = 32; off > 0; off >>= 1) s += __shfl_xor(s, off);
    vals[v] = s;
  }
  __shared__ float red[4][9];
  int lane = tid & 63, w = tid >> 6;
  if (lane == 0) {
#pragma unroll
    for (int v = 0; v < 9; ++v) red[w][v] = vals[v];
  }
  __syncthreads();
  if (tid == 0) {
    float tot[9];
#pragma unroll
    for (int v = 0; v < 9; ++v) tot[v] = red[0][v] + red[1][v] + red[2][v] + red[3][v];
    float rs = rsqrtf(tot[0] / (float)H_DIM + 1e-6f);
    float lg[8], mx = -1e30f;
#pragma unroll
    for (int e = 0; e < 8; ++e) { lg[e] = tot[e + 1] * rs; mx = fmaxf(mx, lg[e]); }
    float pe[8], sum = 0.f;
#pragma unroll
    for (int e = 0; e < 8; ++e) { pe[e] = expf(lg[e] - mx); sum += pe[e]; }
    float inv = 1.f / sum;
#pragma unroll
    for (int e = 0; e < 8; ++e) { pe[e] *= inv; probs[t * 8 + e] = pe[e]; }
    int b1 = 0; float p1 = pe[0];
#pragma unroll
    for (int e = 1; e < 8; ++e) if (pe[e] > p1) { p1 = pe[e]; b1 = e; }
    int b2 = -1; float p2 = -1.f;
#pragma unroll
    for (int e = 0; e < 8; ++e) if (e != b1 && pe[e] > p2) { p2 = pe[e]; b2 = e; }
    float wsum = p1 + p2;
    topw[t * 2] = p1 / wsum;
    topw[t * 2 + 1] = p2 / wsum;
    topi[t * 2] = b1;
    topi[t * 2 + 1] = b2;
    atomicAdd(&counts[b1], 1u);        // slot-0 bucket
    atomicAdd(&counts[8 + b2], 1u);    // slot-1 bucket
  }
}

// ---------------- importance[e] = sum_t probs[t,e] ----------------
__global__ __launch_bounds__(256) void moe_importance_kernel(
    const float* __restrict__ probs, float* __restrict__ impSum) {
  int e = blockIdx.x, tid = threadIdx.x;
  float s = 0.f;
  for (int t = tid; t < T_TOKENS; t += 256) s += probs[t * 8 + e];
  __shared__ float red[256];
  red[tid] = s;
  __syncthreads();
  for (int st = 128; st > 0; st >>= 1) {
    if (tid < st) red[tid] += red[tid + st];
    __syncthreads();
  }
  if (tid == 0) impSum[e] = red[0];
}

// ---------------- tile offsets + aux loss ----------------
__global__ void moe_offsets_aux_kernel(const unsigned int* __restrict__ counts,
                                       const float* __restrict__ impSum,
                                       int* __restrict__ tileOff,
                                       float* __restrict__ out_aux) {
  if (threadIdx.x == 0 && blockIdx.x == 0) {
    int acc = 0;
    for (int b = 0; b < 16; ++b) {
      tileOff[b] = acc;
      acc += (int)((counts[b] + 127u) >> 7);
    }
    tileOff[16] = acc;
    float a = 0.f;
    for (int e = 0; e < 8; ++e) {
      float load = (float)(counts[e] + counts[8 + e]) / (float)PAIRS;
      a += (impSum[e] / (float)T_TOKENS) * load;
    }
    out_aux[0] = a * (float)N_EXPERTS;
  }
}

// ---------------- bucket pairs (expert x slot) ----------------
__global__ __launch_bounds__(256) void moe_assign_kernel(
    const int* __restrict__ topi, const int* __restrict__ tileOff,
    unsigned int* __restrict__ cursors, int* __restrict__ row2pair) {
  int p = blockIdx.x * 256 + threadIdx.x;
  if (p >= PAIRS) return;
  int b = topi[p] + 8 * (p & 1);
  unsigned int pos = atomicAdd(&cursors[b], 1u);
  row2pair[tileOff[b] * 128 + (int)pos] = p;
}

// ---------------- Stage A: P = silu(X@gate^T) * (X@up^T) ----------------
// Persistent blocks, 8 waves (2M x 4N), tile 128 rows x 256 concat-cols
// (gate/up interleaved at 32-col granularity -> silu fuse is in-register).
// Double-buffered LDS; A reg-staged fp32->bf16 (cvt_pk); B via global_load_lds.
// Counted vmcnt: B prefetch stays in flight across both barriers.
__global__ __launch_bounds__(512, 2) void moe_stage_a(
    const float* __restrict__ X,
    const unsigned short* __restrict__ Wg, const unsigned short* __restrict__ Wu,
    const int* __restrict__ row2pair, const int* __restrict__ tileOff,
    unsigned int* __restrict__ workCtr, unsigned short* __restrict__ P) {
  // buf layout: A slices [0,16) at 0, B slices [0,32) at 8192 shorts
  __shared__ __align__(16) unsigned short sAB[2][24576];
  __shared__ int sTok[128];
  __shared__ int sWork;
  const int tid = threadIdx.x;
  const int lane = tid & 63, w = tid >> 6;
  const int wm = w >> 2, wn = w & 3;
  const int lrow = lane & 15, grp = lane >> 4;
  const int rloc = lane >> 3, cch = lane & 7;
  const int swz8 = (cch ^ rloc) * 8;           // source chunk offset (shorts)
  const int ar = tid >> 2, aq = tid & 3;       // A staging: row, quarter
  const int ach0 = ((aq * 2) ^ (ar & 7)) * 8;  // A ds_write chunk slots (shorts)
  const int ach1 = ((aq * 2 + 1) ^ (ar & 7)) * 8;
  const int nTiles = tileOff[16];
  const int nWork = nTiles * 8;

  for (;;) {
    if (tid == 0) sWork = (int)atomicAdd(workCtr, 1u);
    __syncthreads();
    const int item = sWork;
    if (item >= nWork) break;
    const int mt = item % nTiles;
    const int nt = item / nTiles;
    int b = 0;
#pragma unroll
    for (int k = 1; k < 16; ++k) if (tileOff[k] <= mt) b = k;
    const int e = b & 7;
    const int row0 = mt * 128, n0 = nt * 128;
    if (tid < 128) {
      int pr = row2pair[row0 + tid];
      sTok[tid] = (pr >= 0) ? (pr >> 1) : 0;
    }
    __syncthreads();

    const float* aSrc = X + (size_t)sTok[ar] * H_DIM + aq * 16;
    const unsigned short* bSrc[4];
    const size_t wbase = (size_t)e * ((size_t)I_DIM * H_DIM);
#pragma unroll
    for (int i = 0; i < 4; ++i) {
      int s = 4 * w + i;                               // B slice [0,32)
      int col = n0 + (s >> 3) * 32 + (s & 3) * 8 + rloc; // weight I-row
      const unsigned short* basep = (s & 4) ? Wu : Wg;
      bSrc[i] = basep + wbase + (size_t)col * H_DIM + swz8;
    }
    const int bDst = 8192 + 4 * w * 512 + lane * 8;    // shorts, + i*512

    f32x4 acc[4][4] = {};   // n 0..1: gate, n 2..3: up (same phys cols)

    // ---- prologue: stage k=0 into buf 0
    {
      f32x4 a0 = *reinterpret_cast<const f32x4*>(aSrc);
      f32x4 a1 = *reinterpret_cast<const f32x4*>(aSrc + 4);
      f32x4 a2 = *reinterpret_cast<const f32x4*>(aSrc + 8);
      f32x4 a3 = *reinterpret_cast<const f32x4*>(aSrc + 12);
      SB0();
#pragma unroll
      for (int i = 0; i < 4; ++i)
        gll16(bSrc[i], (void*)&sAB[0][bDst + i * 512]);
      SB0();
      u32x4 q0 = {pkbf(a0[0], a0[1]), pkbf(a0[2], a0[3]), pkbf(a1[0], a1[1]), pkbf(a1[2], a1[3])};
      u32x4 q1 = {pkbf(a2[0], a2[1]), pkbf(a2[2], a2[3]), pkbf(a3[0], a3[1]), pkbf(a3[2], a3[3])};
      *reinterpret_cast<u32x4*>(&sAB[0][ar * 64 + ach0]) = q0;
      *reinterpret_cast<u32x4*>(&sAB[0][ar * 64 + ach1]) = q1;
      asm volatile("s_waitcnt lgkmcnt(0)" ::: "memory");
      SB0();
      BAR();
      SB0();
    }

    int cur = 0;
#pragma unroll 1
    for (int kk = 0; kk < 32; ++kk) {
      f32x4 a0, a1, a2, a3;
      if (kk < 31) {
        const float* ap = aSrc + (kk + 1) * 64;
        a0 = *reinterpret_cast<const f32x4*>(ap);
        a1 = *reinterpret_cast<const f32x4*>(ap + 4);
        a2 = *reinterpret_cast<const f32x4*>(ap + 8);
        a3 = *reinterpret_cast<const f32x4*>(ap + 12);
        SB0();
#pragma unroll
        for (int i = 0; i < 4; ++i)
          gll16(bSrc[i] + (kk + 1) * 64, (void*)&sAB[cur ^ 1][bDst + i * 512]);
        SB0();
        asm volatile("s_waitcnt vmcnt(8)" ::: "memory");  // cur-buffer B loads done
      } else {
        asm volatile("s_waitcnt vmcnt(0)" ::: "memory");
      }
      SB0();
      BAR();
      SB0();
#pragma unroll
      for (int ks = 0; ks < 2; ++ks) {
        bfv af[4], bf[4];
        const int co = ((ks * 4 + grp) ^ cch) << 3;
#pragma unroll
        for (int m = 0; m < 4; ++m) {
          int r = wm * 64 + m * 16 + lrow;
          af[m] = *reinterpret_cast<const bfv*>(&sAB[cur][r * 64 + co]);
        }
#pragma unroll
        for (int n = 0; n < 4; ++n) {
          int R = wn * 64 + n * 16 + lrow;
          bf[n] = *reinterpret_cast<const bfv*>(&sAB[cur][8192 + R * 64 + co]);
        }
#pragma unroll
        for (int m = 0; m < 4; ++m)
#pragma unroll
          for (int n = 0; n < 4; ++n)
            acc[m][n] = __builtin_amdgcn_mfma_f32_16x16x32_bf16(af[m], bf[n], acc[m][n], 0, 0, 0);
      }
      if (kk < 31) {
        u32x4 q0 = {pkbf(a0[0], a0[1]), pkbf(a0[2], a0[3]), pkbf(a1[0], a1[1]), pkbf(a1[2], a1[3])};
        u32x4 q1 = {pkbf(a2[0], a2[1]), pkbf(a2[2], a2[3]), pkbf(a3[0], a3[1]), pkbf(a3[2], a3[3])};
        *reinterpret_cast<u32x4*>(&sAB[cur ^ 1][ar * 64 + ach0]) = q0;
        *reinterpret_cast<u32x4*>(&sAB[cur ^ 1][ar * 64 + ach1]) = q1;
        asm volatile("s_waitcnt lgkmcnt(0)" ::: "memory");
      }
      SB0();
      BAR();
      cur ^= 1;
    }

    // epilogue: fuse silu in-register (lane holds g at acc[m][n], u at acc[m][n+2])
    const int rb = grp * 4;
#pragma unroll
    for (int m = 0; m < 4; ++m) {
#pragma unroll
      for (int n = 0; n < 2; ++n) {
#pragma unroll
        for (int j = 0; j < 4; ++j) {
          float g = acc[m][n][j];
          float uu = acc[m][n + 2][j];
          float pv = (g / (1.f + expf(-g))) * uu;
          int rl = wm * 64 + m * 16 + rb + j;
          int cl = n0 + wn * 32 + n * 16 + lrow;
          P[(size_t)(row0 + rl) * I_DIM + cl] = f2bf(pv);
        }
      }
    }
  }
}

// ---------------- Stage B: O = P @ down^T, weighted scatter to out ----------------
// Persistent blocks, 8 waves (2M x 4N), tile 128 rows x 256 H-cols, all-gll16,
// double-buffered, counted vmcnt(6). phase0: out = w*o ; phase1: out += w*o.
__global__ __launch_bounds__(512, 2) void moe_stage_b(
    const unsigned short* __restrict__ Pb, const unsigned short* __restrict__ Wd,
    const int* __restrict__ row2pair, const int* __restrict__ tileOff,
    const float* __restrict__ topw, unsigned int* __restrict__ workCtr,
    float* __restrict__ out, int phase) {
  // buf layout: A(P) slices [0,16) at 0, B(down) slices [0,32) at 8192 shorts
  __shared__ __align__(16) unsigned short sAB[2][24576];
  __shared__ int sPair[128];
  __shared__ int sWork;
  const int tid = threadIdx.x;
  const int lane = tid & 63, w = tid >> 6;
  const int wm = w >> 2, wn = w & 3;
  const int lrow = lane & 15, grp = lane >> 4;
  const int rloc = lane >> 3, cch = lane & 7;
  const int swz8 = (cch ^ rloc) * 8;
  const int t0 = phase ? tileOff[8] : 0;
  const int t1 = phase ? tileOff[16] : tileOff[8];
  const int nTiles = t1 - t0;
  const int nWork = nTiles * 8;
  const int ldsOff = 6 * w * 512 + lane * 8;   // + i*512 (A region then B region)

  for (;;) {
    if (tid == 0) sWork = (int)atomicAdd(workCtr, 1u);
    __syncthreads();
    const int item = sWork;
    if (item >= nWork) break;
    const int mt = t0 + item % nTiles;
    const int nt = item / nTiles;
    int b = 0;
#pragma unroll
    for (int k = 1; k < 16; ++k) if (tileOff[k] <= mt) b = k;
    const int e = b & 7;
    const int row0 = mt * 128, h0 = nt * 256;
    if (tid < 128) sPair[tid] = row2pair[row0 + tid];
    __syncthreads();

    const unsigned short* src[6];
#pragma unroll
    for (int i = 0; i < 6; ++i) {
      int s = 6 * w + i;
      if (s < 16) {
        src[i] = Pb + (size_t)(row0 + s * 8 + rloc) * I_DIM + swz8;
      } else {
        int sb = s - 16;
        src[i] = Wd + (size_t)e * ((size_t)H_DIM * I_DIM) +
                 (size_t)(h0 + sb * 8 + rloc) * I_DIM + swz8;
      }
    }
    // LDS dest offsets (shorts): slice s<16 -> s*512 ; s>=16 -> 8192+(s-16)*512
    // = 6w*512 + lane*8 + i*512 with a +0/+... : since slices are consecutive
    // and A region (16 slices = 8192 shorts) is immediately followed by B region,
    // dest is simply (6w+i)*512 + lane*8 for ALL s.  (16*512 == 8192)
    f32x4 acc[4][4] = {};

    // prologue
#pragma unroll
    for (int i = 0; i < 6; ++i)
      gll16(src[i], (void*)&sAB[0][ldsOff + i * 512]);

    int cur = 0;
#pragma unroll 1
    for (int kk = 0; kk < 16; ++kk) {
      if (kk < 15) {
#pragma unroll
        for (int i = 0; i < 6; ++i)
          gll16(src[i] + (kk + 1) * 64, (void*)&sAB[cur ^ 1][ldsOff + i * 512]);
        SB0();
        asm volatile("s_waitcnt vmcnt(6)" ::: "memory");
      } else {
        asm volatile("s_waitcnt vmcnt(0)" ::: "memory");
      }
      SB0();
      BAR();
      SB0();
#pragma unroll
      for (int ks = 0; ks < 2; ++ks) {
        bfv af[4], bf[4];
        const int co = ((ks * 4 + grp) ^ cch) << 3;
#pragma unroll
        for (int m = 0; m < 4; ++m) {
          int r = wm * 64 + m * 16 + lrow;
          af[m] = *reinterpret_cast<const bfv*>(&sAB[cur][r * 64 + co]);
        }
#pragma unroll
        for (int n = 0; n < 4; ++n) {
          int R = wn * 64 + n * 16 + lrow;
          bf[n] = *reinterpret_cast<const bfv*>(&sAB[cur][8192 + R * 64 + co]);
        }
#pragma unroll
        for (int m = 0; m < 4; ++m)
#pragma unroll
          for (int n = 0; n < 4; ++n)
            acc[m][n] = __builtin_amdgcn_mfma_f32_16x16x32_bf16(af[m], bf[n], acc[m][n], 0, 0, 0);
      }
      SB0();
      BAR();
      cur ^= 1;
    }

    const int rb = grp * 4;
#pragma unroll
    for (int m = 0; m < 4; ++m) {
#pragma unroll
      for (int j = 0; j < 4; ++j) {
        int rl = wm * 64 + m * 16 + rb + j;
        int pr = sPair[rl];
        if (pr < 0) continue;
        float wgt = topw[pr] * 4.f;   // SCALING = E/K
        float* orow = out + (size_t)(pr >> 1) * H_DIM + h0 + wn * 64 + lrow;
        if (phase) {
#pragma unroll
          for (int n = 0; n < 4; ++n) orow[n * 16] += wgt * acc[m][n][j];
        } else {
#pragma unroll
          for (int n = 0; n < 4; ++n) orow[n * 16] = wgt * acc[m][n][j];
        }
      }
    }
  }
}

// ---------------- launch ----------------
// ws layout (bytes), REQ = 105,325,056:
//   P        @ 0           : 18432*1024*2 = 37,748,736
//   probs    @ 37,748,736  : 262,144
//   topw     @ 38,010,880  : 65,536
//   topi     @ 38,076,416  : 65,536
//   row2pair @ 38,141,952  : 73,728
//   ctrl     @ 38,215,680  : 512  (counts[16] cursors[16] impSum[8] tileOff[17] workCtrs@384)
//   W1       @ 38,216,192  : 33,554,432  (gate bf16; reused for down bf16)
//   W2       @ 71,770,624  : 33,554,432  (up bf16)
extern "C" void kernel_launch(void* const* d_in, const int* in_sizes, int n_in,
                              void* d_out, int out_size, void* d_ws, size_t ws_size,
                              hipStream_t stream) {
  const float* X = (const float*)d_in[0];
  const float* norm_w = (const float*)d_in[1];
  const float* router_w = (const float*)d_in[2];
  const float* gate_w = (const float*)d_in[3];
  const float* up_w = (const float*)d_in[4];
  const float* down_w = (const float*)d_in[5];
  float* out = (float*)d_out;

  char* ws = (char*)d_ws;
  unsigned short* P = (unsigned short*)(ws);
  float* probs = (float*)(ws + 37748736);
  float* topw = (float*)(ws + 38010880);
  int* topi = (int*)(ws + 38076416);
  int* row2pair = (int*)(ws + 38141952);
  char* ctrl = ws + 38215680;
  unsigned int* counts = (unsigned int*)(ctrl);
  unsigned int* cursors = (unsigned int*)(ctrl + 64);
  float* impSum = (float*)(ctrl + 128);
  int* tileOff = (int*)(ctrl + 192);
  unsigned int* wcA = (unsigned int*)(ctrl + 384);
  unsigned int* wcB0 = (unsigned int*)(ctrl + 388);
  unsigned int* wcB1 = (unsigned int*)(ctrl + 392);
  unsigned short* W1 = (unsigned short*)(ws + 38216192);   // gate, then down
  unsigned short* W2 = (unsigned short*)(ws + 71770624);   // up

  hipMemsetAsync(ctrl, 0, 512, stream);
  hipMemsetAsync(row2pair, 0xFF, (size_t)TOT_ROWS * 4, stream);

  const int N8 = (N_EXPERTS * I_DIM * H_DIM) / 8;   // 2,097,152
  moe_convert_kernel<<<N8 / 256, 256, 0, stream>>>(gate_w, W1, N8);
  moe_convert_kernel<<<N8 / 256, 256, 0, stream>>>(up_w, W2, N8);

  moe_router_kernel<<<T_TOKENS, 256, 0, stream>>>(X, norm_w, router_w, probs, topw, topi, counts);
  moe_importance_kernel<<<N_EXPERTS, 256, 0, stream>>>(probs, impSum);
  moe_offsets_aux_kernel<<<1, 64, 0, stream>>>(counts, impSum, tileOff, out + 16777216);
  moe_assign_kernel<<<PAIRS / 256, 256, 0, stream>>>(topi, tileOff, cursors, row2pair);

  moe_stage_a<<<256, 512, 0, stream>>>(X, W1, W2, row2pair, tileOff, wcA, P);
  moe_convert_kernel<<<N8 / 256, 256, 0, stream>>>(down_w, W1, N8);
  moe_stage_b<<<256, 512, 0, stream>>>(P, W1, row2pair, tileOff, topw, wcB0, out, 0);
  moe_stage_b<<<256, 512, 0, stream>>>(P, W1, row2pair, tileOff, topw, wcB1, out, 1);
}

// Round 6
// 705.359 us; speedup vs baseline: 1.0915x; 1.0915x over previous
//
#include <hip/hip_runtime.h>
#include <hip/hip_bf16.h>
#include <cstdint>

// Problem constants (B=4, S=2048, H=2048, I=1024, E=8, K=2)
#define T_TOKENS 8192
#define H_DIM 2048
#define I_DIM 1024
#define N_EXPERTS 8
#define PAIRS (T_TOKENS * 2)
#define TOT_TILES 144            // sum_b ceil(n_b/128) <= 16384/128 + 16
#define TOT_ROWS (TOT_TILES * 128)

using f32x4 = __attribute__((ext_vector_type(4))) float;
using bfv   = __attribute__((ext_vector_type(8))) short;   // MFMA a/b frag (8 bf16)
using u16x8 = __attribute__((ext_vector_type(8))) unsigned short;

typedef __attribute__((address_space(3))) unsigned int lds_u32;
typedef __attribute__((address_space(1))) unsigned int glb_u32;

__device__ __forceinline__ void gll16(const void* g, void* l) {
  __builtin_amdgcn_global_load_lds((const glb_u32*)g, (lds_u32*)l, 16, 0, 0);
}
#define SB0() __builtin_amdgcn_sched_barrier(0)
#define BAR() __builtin_amdgcn_s_barrier()

__device__ inline unsigned short f2bf(float f) {
  unsigned int u = __float_as_uint(f);
  u += 0x7FFFu + ((u >> 16) & 1u);          // RTN-even
  return (unsigned short)(u >> 16);
}

// ---------------- fp32 -> bf16 bulk convert ----------------
__global__ __launch_bounds__(256) void moe_convert_kernel(
    const float* __restrict__ src, unsigned short* __restrict__ dst, int n8) {
  int i = blockIdx.x * 256 + threadIdx.x;
  if (i >= n8) return;
  size_t o = (size_t)i * 8;
  f32x4 a = *reinterpret_cast<const f32x4*>(src + o);
  f32x4 b = *reinterpret_cast<const f32x4*>(src + o + 4);
  u16x8 r = {f2bf(a[0]), f2bf(a[1]), f2bf(a[2]), f2bf(a[3]),
             f2bf(b[0]), f2bf(b[1]), f2bf(b[2]), f2bf(b[3])};
  *reinterpret_cast<u16x8*>(dst + o) = r;
}

// ---------------- Router: RMSNorm folded into logits, softmax, top-2 (fp32) ----------------
// Also writes the bf16 copy of X (free: X is being read anyway).
__global__ __launch_bounds__(256) void moe_router_kernel(
    const float* __restrict__ X, const float* __restrict__ norm_w,
    const float* __restrict__ rw, float* __restrict__ probs,
    float* __restrict__ topw, int* __restrict__ topi,
    unsigned int* __restrict__ counts, unsigned short* __restrict__ Xb) {
  int t = blockIdx.x;
  int tid = threadIdx.x;
  const float* x = X + (size_t)t * H_DIM;
  int base = tid * 8;
  f32x4 v0 = *reinterpret_cast<const f32x4*>(x + base);
  f32x4 v1 = *reinterpret_cast<const f32x4*>(x + base + 4);
  u16x8 bx = {f2bf(v0[0]), f2bf(v0[1]), f2bf(v0[2]), f2bf(v0[3]),
              f2bf(v1[0]), f2bf(v1[1]), f2bf(v1[2]), f2bf(v1[3])};
  *reinterpret_cast<u16x8*>(Xb + (size_t)t * H_DIM + base) = bx;
  f32x4 nw0 = *reinterpret_cast<const f32x4*>(norm_w + base);
  f32x4 nw1 = *reinterpret_cast<const f32x4*>(norm_w + base + 4);
  float vals[9];
  vals[0] = v0[0]*v0[0] + v0[1]*v0[1] + v0[2]*v0[2] + v0[3]*v0[3]
          + v1[0]*v1[0] + v1[1]*v1[1] + v1[2]*v1[2] + v1[3]*v1[3];
  f32x4 a0 = v0 * nw0, a1 = v1 * nw1;
#pragma unroll
  for (int e = 0; e < 8; ++e) {
    const float* r = rw + e * H_DIM + base;
    f32x4 r0 = *reinterpret_cast<const f32x4*>(r);
    f32x4 r1 = *reinterpret_cast<const f32x4*>(r + 4);
    f32x4 d = a0 * r0 + a1 * r1;
    vals[e + 1] = d[0] + d[1] + d[2] + d[3];
  }
#pragma unroll
  for (int v = 0; v < 9; ++v) {
    float s = vals[v];
#pragma unroll
    for (int off = 32; off > 0; off >>= 1) s += __shfl_xor(s, off);
    vals[v] = s;
  }
  __shared__ float red[4][9];
  int lane = tid & 63, w = tid >> 6;
  if (lane == 0) {
#pragma unroll
    for (int v = 0; v < 9; ++v) red[w][v] = vals[v];
  }
  __syncthreads();
  if (tid == 0) {
    float tot[9];
#pragma unroll
    for (int v = 0; v < 9; ++v) tot[v] = red[0][v] + red[1][v] + red[2][v] + red[3][v];
    float rs = rsqrtf(tot[0] / (float)H_DIM + 1e-6f);
    float lg[8], mx = -1e30f;
#pragma unroll
    for (int e = 0; e < 8; ++e) { lg[e] = tot[e + 1] * rs; mx = fmaxf(mx, lg[e]); }
    float pe[8], sum = 0.f;
#pragma unroll
    for (int e = 0; e < 8; ++e) { pe[e] = expf(lg[e] - mx); sum += pe[e]; }
    float inv = 1.f / sum;
#pragma unroll
    for (int e = 0; e < 8; ++e) { pe[e] *= inv; probs[t * 8 + e] = pe[e]; }
    int b1 = 0; float p1 = pe[0];
#pragma unroll
    for (int e = 1; e < 8; ++e) if (pe[e] > p1) { p1 = pe[e]; b1 = e; }
    int b2 = -1; float p2 = -1.f;
#pragma unroll
    for (int e = 0; e < 8; ++e) if (e != b1 && pe[e] > p2) { p2 = pe[e]; b2 = e; }
    float wsum = p1 + p2;
    topw[t * 2] = p1 / wsum;
    topw[t * 2 + 1] = p2 / wsum;
    topi[t * 2] = b1;
    topi[t * 2 + 1] = b2;
    atomicAdd(&counts[b1], 1u);        // slot-0 bucket
    atomicAdd(&counts[8 + b2], 1u);    // slot-1 bucket
  }
}

// ---------------- importance[e] = sum_t probs[t,e] ----------------
__global__ __launch_bounds__(256) void moe_importance_kernel(
    const float* __restrict__ probs, float* __restrict__ impSum) {
  int e = blockIdx.x, tid = threadIdx.x;
  float s = 0.f;
  for (int t = tid; t < T_TOKENS; t += 256) s += probs[t * 8 + e];
  __shared__ float red[256];
  red[tid] = s;
  __syncthreads();
  for (int st = 128; st > 0; st >>= 1) {
    if (tid < st) red[tid] += red[tid + st];
    __syncthreads();
  }
  if (tid == 0) impSum[e] = red[0];
}

// ---------------- tile offsets + aux loss ----------------
__global__ void moe_offsets_aux_kernel(const unsigned int* __restrict__ counts,
                                       const float* __restrict__ impSum,
                                       int* __restrict__ tileOff,
                                       float* __restrict__ out_aux) {
  if (threadIdx.x == 0 && blockIdx.x == 0) {
    int acc = 0;
    for (int b = 0; b < 16; ++b) {
      tileOff[b] = acc;
      acc += (int)((counts[b] + 127u) >> 7);
    }
    tileOff[16] = acc;
    float a = 0.f;
    for (int e = 0; e < 8; ++e) {
      float load = (float)(counts[e] + counts[8 + e]) / (float)PAIRS;
      a += (impSum[e] / (float)T_TOKENS) * load;
    }
    out_aux[0] = a * (float)N_EXPERTS;
  }
}

// ---------------- bucket pairs (expert x slot) ----------------
__global__ __launch_bounds__(256) void moe_assign_kernel(
    const int* __restrict__ topi, const int* __restrict__ tileOff,
    unsigned int* __restrict__ cursors, int* __restrict__ row2pair) {
  int p = blockIdx.x * 256 + threadIdx.x;
  if (p >= PAIRS) return;
  int b = topi[p] + 8 * (p & 1);
  unsigned int pos = atomicAdd(&cursors[b], 1u);
  row2pair[tileOff[b] * 128 + (int)pos] = p;
}

// ======================= GEMM stages =======================
// Shared geometry: BM=128 rows, BN=256 cols, BK=32, 256 threads = 4 waves.
// Wave w owns cols [w*64, w*64+64) x all 128 rows (wave-tile 128x64):
//   per K-step: 8 A-frag reads + 4 B-frag reads -> 32 MFMA (ratio 0.375).
// LDS per buffer: A 128x32 + B 256x32 shorts = 24 KB; dbuf = 48 KB -> 2 blocks/CU.
// Staging: 6 gll16/thread/K-step (it 0..1 = A, 2..5 = B); source-side chunk
// swizzle c^(row&3) matches read swizzle grp^(lane&3) (row&3 == lane&3 at read).
// Pipeline: prefetch next K-step, s_waitcnt vmcnt(6), barrier, MFMA, barrier.
// Stage A K-extent: H_DIM/32 = 64 steps.  Stage B: I_DIM/32 = 32 steps.

// ---------------- Stage A: P = silu(X@gate^T) * (X@up^T) ----------------
// Concat-N: within a wave's 64 cols, cols [0,32) = gate, [32,64) = up of the
// SAME I-columns -> silu fuse fully in-register (acc[m][n] g / acc[m][n+2] u).
__global__ __launch_bounds__(256, 2) void moe_stage_a(
    const unsigned short* __restrict__ Xb,
    const unsigned short* __restrict__ Wg, const unsigned short* __restrict__ Wu,
    const int* __restrict__ row2pair, const int* __restrict__ tileOff,
    unsigned int* __restrict__ workCtr, unsigned short* __restrict__ P) {
  __shared__ __align__(16) unsigned short sAB[2][12288];
  __shared__ int sTok[128];
  __shared__ int sWork;
  const int tid = threadIdx.x;
  const int lane = tid & 63, w = tid >> 6;
  const int lrow = lane & 15, grp = lane >> 4;
  const int s8 = ((tid & 3) ^ ((tid >> 2) & 3)) << 3;   // src chunk offset (shorts)
  const int rsw = (grp ^ (lane & 3)) << 3;              // read phys-chunk offset
  const int nTiles = tileOff[16];
  const int nWork = nTiles * 8;

  for (;;) {
    if (tid == 0) sWork = (int)atomicAdd(workCtr, 1u);
    __syncthreads();
    const int item = sWork;
    if (item >= nWork) break;
    const int mt = item % nTiles;
    const int nt = item / nTiles;       // I-block [nt*128, nt*128+128)
    int b = 0;
#pragma unroll
    for (int k = 1; k < 16; ++k) if (tileOff[k] <= mt) b = k;
    const int e = b & 7;
    const int row0 = mt * 128;
    if (tid < 128) {
      int pr = row2pair[row0 + tid];
      sTok[tid] = (pr >= 0) ? (pr >> 1) : 0;
    }
    __syncthreads();

    const size_t wbase = (size_t)e * ((size_t)I_DIM * H_DIM);
    const unsigned short* src[6];
#pragma unroll
    for (int it = 0; it < 2; ++it) {
      int ra = it * 64 + (tid >> 2);
      src[it] = Xb + (size_t)sTok[ra] * H_DIM + s8;
    }
#pragma unroll
    for (int it = 2; it < 6; ++it) {
      int c = (it - 2) * 64 + (tid >> 2);   // LDS col [0,256)
      int wq = c >> 6, r6 = c & 63;
      int irow = nt * 128 + wq * 32 + (r6 & 31);
      const unsigned short* basep = (r6 >> 5) ? Wu : Wg;
      src[it] = basep + wbase + (size_t)irow * H_DIM + s8;
    }

    f32x4 acc[8][4] = {};

#pragma unroll
    for (int i = 0; i < 6; ++i)
      gll16(src[i], (void*)&sAB[0][(i * 256 + tid) * 8]);

    int cur = 0;
#pragma unroll 1
    for (int kk = 0; kk < 64; ++kk) {          // 64 * BK32 = 2048 = H_DIM
      if (kk < 63) {
#pragma unroll
        for (int i = 0; i < 6; ++i)
          gll16(src[i] + ((kk + 1) << 5), (void*)&sAB[cur ^ 1][(i * 256 + tid) * 8]);
        SB0();
        asm volatile("s_waitcnt vmcnt(6)" ::: "memory");
      } else {
        asm volatile("s_waitcnt vmcnt(0)" ::: "memory");
      }
      SB0();
      BAR();
      SB0();
      bfv af[8], bf[4];
#pragma unroll
      for (int m = 0; m < 8; ++m)
        af[m] = *reinterpret_cast<const bfv*>(&sAB[cur][(m * 16 + lrow) * 32 + rsw]);
#pragma unroll
      for (int n = 0; n < 4; ++n)
        bf[n] = *reinterpret_cast<const bfv*>(&sAB[cur][4096 + (w * 64 + n * 16 + lrow) * 32 + rsw]);
      __builtin_amdgcn_s_setprio(1);
#pragma unroll
      for (int m = 0; m < 8; ++m)
#pragma unroll
        for (int n = 0; n < 4; ++n)
          acc[m][n] = __builtin_amdgcn_mfma_f32_16x16x32_bf16(af[m], bf[n], acc[m][n], 0, 0, 0);
      __builtin_amdgcn_s_setprio(0);
      SB0();
      BAR();
      cur ^= 1;
    }

    // epilogue: silu fuse in-register; C/D: row = grp*4+j, col = lrow
#pragma unroll
    for (int m = 0; m < 8; ++m) {
#pragma unroll
      for (int n = 0; n < 2; ++n) {
#pragma unroll
        for (int j = 0; j < 4; ++j) {
          float g = acc[m][n][j];
          float uu = acc[m][n + 2][j];
          float pv = (g / (1.f + expf(-g))) * uu;
          int row = row0 + m * 16 + grp * 4 + j;
          int col = nt * 128 + w * 32 + n * 16 + lrow;
          P[(size_t)row * I_DIM + col] = f2bf(pv);
        }
      }
    }
  }
}

// ---------------- Stage B: O = P @ down^T, weighted scatter to out ----------------
// phase 0 (slot-0 buckets): out = 4*w*o ; phase 1 (slot-1): out += 4*w*o.
__global__ __launch_bounds__(256, 2) void moe_stage_b(
    const unsigned short* __restrict__ Pb, const unsigned short* __restrict__ Wd,
    const int* __restrict__ row2pair, const int* __restrict__ tileOff,
    const float* __restrict__ topw, unsigned int* __restrict__ workCtr,
    float* __restrict__ out, int phase) {
  __shared__ __align__(16) unsigned short sAB[2][12288];
  __shared__ int sPair[128];
  __shared__ int sWork;
  const int tid = threadIdx.x;
  const int lane = tid & 63, w = tid >> 6;
  const int lrow = lane & 15, grp = lane >> 4;
  const int s8 = ((tid & 3) ^ ((tid >> 2) & 3)) << 3;
  const int rsw = (grp ^ (lane & 3)) << 3;
  const int t0 = phase ? tileOff[8] : 0;
  const int t1 = phase ? tileOff[16] : tileOff[8];
  const int nTiles = t1 - t0;
  const int nWork = nTiles * 8;

  for (;;) {
    if (tid == 0) sWork = (int)atomicAdd(workCtr, 1u);
    __syncthreads();
    const int item = sWork;
    if (item >= nWork) break;
    const int mt = t0 + item % nTiles;
    const int nt = item / nTiles;       // H-block [nt*256, nt*256+256)
    int b = 0;
#pragma unroll
    for (int k = 1; k < 16; ++k) if (tileOff[k] <= mt) b = k;
    const int e = b & 7;
    const int row0 = mt * 128, h0 = nt * 256;
    if (tid < 128) sPair[tid] = row2pair[row0 + tid];
    __syncthreads();

    const unsigned short* src[6];
#pragma unroll
    for (int it = 0; it < 2; ++it) {
      int ra = it * 64 + (tid >> 2);
      src[it] = Pb + (size_t)(row0 + ra) * I_DIM + s8;
    }
#pragma unroll
    for (int it = 2; it < 6; ++it) {
      int c = (it - 2) * 64 + (tid >> 2);
      src[it] = Wd + (size_t)e * ((size_t)H_DIM * I_DIM) + (size_t)(h0 + c) * I_DIM + s8;
    }

    f32x4 acc[8][4] = {};

#pragma unroll
    for (int i = 0; i < 6; ++i)
      gll16(src[i], (void*)&sAB[0][(i * 256 + tid) * 8]);

    int cur = 0;
#pragma unroll 1
    for (int kk = 0; kk < 32; ++kk) {          // 32 * BK32 = 1024 = I_DIM
      if (kk < 31) {
#pragma unroll
        for (int i = 0; i < 6; ++i)
          gll16(src[i] + ((kk + 1) << 5), (void*)&sAB[cur ^ 1][(i * 256 + tid) * 8]);
        SB0();
        asm volatile("s_waitcnt vmcnt(6)" ::: "memory");
      } else {
        asm volatile("s_waitcnt vmcnt(0)" ::: "memory");
      }
      SB0();
      BAR();
      SB0();
      bfv af[8], bf[4];
#pragma unroll
      for (int m = 0; m < 8; ++m)
        af[m] = *reinterpret_cast<const bfv*>(&sAB[cur][(m * 16 + lrow) * 32 + rsw]);
#pragma unroll
      for (int n = 0; n < 4; ++n)
        bf[n] = *reinterpret_cast<const bfv*>(&sAB[cur][4096 + (w * 64 + n * 16 + lrow) * 32 + rsw]);
      __builtin_amdgcn_s_setprio(1);
#pragma unroll
      for (int m = 0; m < 8; ++m)
#pragma unroll
        for (int n = 0; n < 4; ++n)
          acc[m][n] = __builtin_amdgcn_mfma_f32_16x16x32_bf16(af[m], bf[n], acc[m][n], 0, 0, 0);
      __builtin_amdgcn_s_setprio(0);
      SB0();
      BAR();
      cur ^= 1;
    }

#pragma unroll
    for (int m = 0; m < 8; ++m) {
#pragma unroll
      for (int j = 0; j < 4; ++j) {
        int rl = m * 16 + grp * 4 + j;
        int pr = sPair[rl];
        if (pr < 0) continue;
        float wgt = topw[pr] * 4.f;   // SCALING = E/K
        float* orow = out + (size_t)(pr >> 1) * H_DIM + h0 + w * 64 + lrow;
        if (phase) {
#pragma unroll
          for (int n = 0; n < 4; ++n) orow[n * 16] += wgt * acc[m][n][j];
        } else {
#pragma unroll
          for (int n = 0; n < 4; ++n) orow[n * 16] = wgt * acc[m][n][j];
        }
      }
    }
  }
}

// ---------------- launch ----------------
// ws layout (bytes), REQ = 138,879,488 (proven available in round 2):
//   P        @ 0           : 18432*1024*2 = 37,748,736
//   probs    @ 37,748,736  : 262,144
//   topw     @ 38,010,880  : 65,536
//   topi     @ 38,076,416  : 65,536
//   row2pair @ 38,141,952  : 73,728
//   ctrl     @ 38,215,680  : 512  (counts[16] cursors[16] impSum[8] tileOff[17] workCtrs@384)
//   W1       @ 38,216,192  : 33,554,432  (gate bf16; reused for down bf16)
//   W2       @ 71,770,624  : 33,554,432  (up bf16)
//   Xb       @ 105,325,056 : 33,554,432  (X bf16)
extern "C" void kernel_launch(void* const* d_in, const int* in_sizes, int n_in,
                              void* d_out, int out_size, void* d_ws, size_t ws_size,
                              hipStream_t stream) {
  const float* X = (const float*)d_in[0];
  const float* norm_w = (const float*)d_in[1];
  const float* router_w = (const float*)d_in[2];
  const float* gate_w = (const float*)d_in[3];
  const float* up_w = (const float*)d_in[4];
  const float* down_w = (const float*)d_in[5];
  float* out = (float*)d_out;

  char* ws = (char*)d_ws;
  unsigned short* P = (unsigned short*)(ws);
  float* probs = (float*)(ws + 37748736);
  float* topw = (float*)(ws + 38010880);
  int* topi = (int*)(ws + 38076416);
  int* row2pair = (int*)(ws + 38141952);
  char* ctrl = ws + 38215680;
  unsigned int* counts = (unsigned int*)(ctrl);
  unsigned int* cursors = (unsigned int*)(ctrl + 64);
  float* impSum = (float*)(ctrl + 128);
  int* tileOff = (int*)(ctrl + 192);
  unsigned int* wcA = (unsigned int*)(ctrl + 384);
  unsigned int* wcB0 = (unsigned int*)(ctrl + 388);
  unsigned int* wcB1 = (unsigned int*)(ctrl + 392);
  unsigned short* W1 = (unsigned short*)(ws + 38216192);   // gate, then down
  unsigned short* W2 = (unsigned short*)(ws + 71770624);   // up
  unsigned short* Xb = (unsigned short*)(ws + 105325056);

  hipMemsetAsync(ctrl, 0, 512, stream);
  hipMemsetAsync(row2pair, 0xFF, (size_t)TOT_ROWS * 4, stream);

  const int N8 = (N_EXPERTS * I_DIM * H_DIM) / 8;   // 2,097,152
  moe_convert_kernel<<<N8 / 256, 256, 0, stream>>>(gate_w, W1, N8);
  moe_convert_kernel<<<N8 / 256, 256, 0, stream>>>(up_w, W2, N8);

  moe_router_kernel<<<T_TOKENS, 256, 0, stream>>>(X, norm_w, router_w, probs, topw, topi,
                                                  counts, Xb);
  moe_importance_kernel<<<N_EXPERTS, 256, 0, stream>>>(probs, impSum);
  moe_offsets_aux_kernel<<<1, 64, 0, stream>>>(counts, impSum, tileOff, out + 16777216);
  moe_assign_kernel<<<PAIRS / 256, 256, 0, stream>>>(topi, tileOff, cursors, row2pair);

  moe_stage_a<<<512, 256, 0, stream>>>(Xb, W1, W2, row2pair, tileOff, wcA, P);
  moe_convert_kernel<<<N8 / 256, 256, 0, stream>>>(down_w, W1, N8);
  moe_stage_b<<<512, 256, 0, stream>>>(P, W1, row2pair, tileOff, topw, wcB0, out, 0);
  moe_stage_b<<<512, 256, 0, stream>>>(P, W1, row2pair, tileOff, topw, wcB1, out, 1);
}